// Round 3
// baseline (255.505 us; speedup 1.0000x reference)
//
#include <hip/hip_runtime.h>
#include <stdint.h>

// ---------------------------------------------------------------------------
// Speaker pairwise loss.  sim = F·F^T is SYMMETRIC: process only 128x128
// tiles with J >= I (2080 of 4096).  Off-diagonal tiles contribute row-wise
// stats (rows of I) AND column-wise stats (rows of J, via transpose).
//   convert: fp32 feats -> bf16 once (ws)
//   pass1: per-row min(pos sims), max(neg sims)  (ordered-uint atomic min/max)
//   pass2: per-row masked exp sums with dynamic thresholds from pass1
//   finalize: loss, prec1
// Staging: global_load_lds width=16 from bf16 buffer, XOR-swizzled (no pad).
// ws: minord[B] u32 | maxord[B] u32 | psum[B] f32 | nsum[B] f32 | featsbf16[B*D]
// ---------------------------------------------------------------------------

typedef __attribute__((ext_vector_type(8))) short short8;   // 8 bf16 (4 VGPRs)
typedef __attribute__((ext_vector_type(4))) float floatx4;  // MFMA C/D

constexpr int D = 256;
constexpr int BM = 128;
constexpr int BK = 64;
constexpr int NT = 64;           // 8192 / 128 tile-rows
constexpr int NBLK = NT * (NT + 1) / 2;   // 2080

constexpr unsigned ORD_POS_INF = 0xFF800000u;  // ford(+inf)
constexpr unsigned ORD_NEG_INF = 0x007FFFFFu;  // ford(-inf)

__device__ __forceinline__ unsigned ford(float f) {
  unsigned u = __float_as_uint(f);
  return (u & 0x80000000u) ? ~u : (u | 0x80000000u);
}
__device__ __forceinline__ float fdec(unsigned x) {
  unsigned u = (x & 0x80000000u) ? (x ^ 0x80000000u) : ~x;
  return __uint_as_float(u);
}
__device__ __forceinline__ unsigned f2bf(float f) {  // fp32 -> bf16 bits, RNE
  unsigned u = __float_as_uint(f);
  return (u + 0x7FFFu + ((u >> 16) & 1u)) >> 16;
}

__device__ __forceinline__ void gl_lds16(const void* g, void* l) {
  __builtin_amdgcn_global_load_lds(
      (const __attribute__((address_space(1))) unsigned int*)g,
      (__attribute__((address_space(3))) unsigned int*)l, 16, 0, 0);
}

__global__ void init_kernel(unsigned* __restrict__ minord, unsigned* __restrict__ maxord,
                            float* __restrict__ psum, float* __restrict__ nsum, int Bn) {
  int i = blockIdx.x * blockDim.x + threadIdx.x;
  if (i < Bn) {
    minord[i] = ORD_POS_INF;
    maxord[i] = ORD_NEG_INF;
    psum[i] = 0.f;
    nsum[i] = 0.f;
  }
}

__global__ void convert_kernel(const float* __restrict__ feats,
                               unsigned short* __restrict__ fb, int n4) {
  int i = blockIdx.x * blockDim.x + threadIdx.x;
  if (i < n4) {
    float4 v = ((const float4*)feats)[i];
    unsigned lo = f2bf(v.x) | (f2bf(v.y) << 16);
    unsigned hi = f2bf(v.z) | (f2bf(v.w) << 16);
    ((uint2*)fb)[i] = make_uint2(lo, hi);
  }
}

template <int PASS>
__global__ __launch_bounds__(256)
void pair_kernel(const unsigned short* __restrict__ fb, const int* __restrict__ labels,
                 unsigned* __restrict__ minord, unsigned* __restrict__ maxord,
                 float* __restrict__ psum, float* __restrict__ nsum) {
  __shared__ short As[BM * BK];   // 16KB, unpadded (global_load_lds), XOR swizzle
  __shared__ short Bs[BM * BK];   // 16KB
  __shared__ int   labA[BM];
  __shared__ int   labB[BM];
  __shared__ float tmnA[BM], tmxA[BM];   // pass2 row thresholds
  __shared__ float tmnB[BM], tmxB[BM];   // pass2 col thresholds

  // ---- decode triangular block index: tiles (I,J) with J >= I ----
  const int t = blockIdx.x;
  int I = (int)((129.0f - sqrtf(16641.0f - 8.0f * (float)t)) * 0.5f);
  while (I * (129 - I) / 2 > t) --I;
  while ((I + 1) * (129 - (I + 1)) / 2 <= t) ++I;
  const int J = I + (t - I * (129 - I) / 2);
  const bool diag = (I == J);

  const int row0 = I * BM;
  const int col0 = J * BM;

  const int tid  = threadIdx.x;
  const int lane = tid & 63;
  const int wave = tid >> 6;
  const int l15  = lane & 15;
  const int quad = lane >> 4;
  const int wr   = (wave >> 1) * 64;
  const int wc   = (wave & 1) * 64;

  const float ONE_EPS = 1.0f - 1e-5f;
  const float INF = __builtin_inff();

  if (tid < BM) {
    labA[tid] = labels[row0 + tid];
    labB[tid] = labels[col0 + tid];
    if (PASS == 2) {
      tmnA[tid] = fdec(minord[row0 + tid]) - 0.1f;
      tmxA[tid] = fdec(maxord[row0 + tid]) + 0.1f;
      tmnB[tid] = fdec(minord[col0 + tid]) - 0.1f;
      tmxB[tid] = fdec(maxord[col0 + tid]) + 0.1f;
    }
  }

  // staging geometry
  const int srow = (wave << 5) + (lane >> 3);
  const int slot = lane & 7;

  int arow[4], brow[4];
#pragma unroll
  for (int i = 0; i < 4; ++i) {
    arow[i] = wr + i * 16 + l15;
    brow[i] = wc + i * 16 + l15;
  }

  floatx4 acc[4][4];
#pragma unroll
  for (int rf = 0; rf < 4; ++rf)
#pragma unroll
    for (int cf = 0; cf < 4; ++cf)
      acc[rf][cf] = (floatx4)(0.f);

  for (int kc = 0; kc < 4; ++kc) {
#pragma unroll
    for (int j = 0; j < 4; ++j) {
      int r = srow + 8 * j;
      int sw = (slot ^ (r & 7)) << 4;
      const char* ga = (const char*)fb + (((size_t)(row0 + r)) << 9) + (kc << 7) + sw;
      gl_lds16(ga, (char*)As + (r << 7) + (slot << 4));
      const char* gb = (const char*)fb + (((size_t)(col0 + r)) << 9) + (kc << 7) + sw;
      gl_lds16(gb, (char*)Bs + (r << 7) + (slot << 4));
    }
    __syncthreads();
#pragma unroll
    for (int ks = 0; ks < 2; ++ks) {
      const int g = ks * 4 + quad;
      short8 a[4], b[4];
#pragma unroll
      for (int rf = 0; rf < 4; ++rf)
        a[rf] = *(const short8*)(As + arow[rf] * 64 + ((g ^ (arow[rf] & 7)) << 3));
#pragma unroll
      for (int cf = 0; cf < 4; ++cf)
        b[cf] = *(const short8*)(Bs + brow[cf] * 64 + ((g ^ (brow[cf] & 7)) << 3));
#pragma unroll
      for (int rf = 0; rf < 4; ++rf)
#pragma unroll
        for (int cf = 0; cf < 4; ++cf)
          acc[rf][cf] = __builtin_amdgcn_mfma_f32_16x16x32_bf16(a[rf], b[cf], acc[rf][cf], 0, 0, 0);
    }
    __syncthreads();
  }

  // ---- epilogue: row stats (always) + col stats (off-diagonal only) ----
  int labc[4];
  float tmnBc[4], tmxBc[4];
#pragma unroll
  for (int cf = 0; cf < 4; ++cf) {
    labc[cf] = labB[wc + cf * 16 + l15];
    if (PASS == 2) { tmnBc[cf] = tmnB[wc + cf * 16 + l15]; tmxBc[cf] = tmxB[wc + cf * 16 + l15]; }
  }

  float s0[16], s1[16];   // row stats per (rf,r)
  float c0[4],  c1[4];    // col stats per cf
#pragma unroll
  for (int i = 0; i < 16; ++i) {
    s0[i] = (PASS == 1) ? INF : 0.f;
    s1[i] = (PASS == 1) ? -INF : 0.f;
  }
#pragma unroll
  for (int i = 0; i < 4; ++i) {
    c0[i] = (PASS == 1) ? INF : 0.f;
    c1[i] = (PASS == 1) ? -INF : 0.f;
  }

#pragma unroll
  for (int rf = 0; rf < 4; ++rf) {
#pragma unroll
    for (int r = 0; r < 4; ++r) {
      const int ri = wr + rf * 16 + quad * 4 + r;
      const int lr = labA[ri];
      float tmnR = 0.f, tmxR = 0.f;
      if (PASS == 2) { tmnR = tmnA[ri]; tmxR = tmxA[ri]; }
#pragma unroll
      for (int cf = 0; cf < 4; ++cf) {
        float sim = acc[rf][cf][r];
        bool same = (lr == labc[cf]);
        bool posok = same && (sim < ONE_EPS);
        if (PASS == 1) {
          float pc = posok ? sim : INF;
          float nc = same ? -INF : sim;
          s0[rf * 4 + r] = fminf(s0[rf * 4 + r], pc);
          s1[rf * 4 + r] = fmaxf(s1[rf * 4 + r], nc);
          c0[cf] = fminf(c0[cf], pc);
          c1[cf] = fmaxf(c1[cf], nc);
        } else {
          if (posok) {
            float e = __expf(fmaf(-2.f, sim, 1.f));      // exp(-2(sim-.5))
            if (sim < tmxR)      s0[rf * 4 + r] += e;
            if (sim < tmxBc[cf]) c0[cf] += e;
          } else if (!same) {
            float e = (sim > 0.22f) ? __expf(fmaf(50.f, sim, -25.f)) : 0.f;
            if (sim > tmnR)      s1[rf * 4 + r] += 1e-30f + e;
            if (sim > tmnBc[cf]) c1[cf] += 1e-30f + e;
          }
        }
      }
    }
  }

  // ---- row reduction: over l15 (cols), atomic per row ----
#pragma unroll
  for (int rf = 0; rf < 4; ++rf) {
#pragma unroll
    for (int r = 0; r < 4; ++r) {
      const int grow = row0 + wr + rf * 16 + quad * 4 + r;
      float v = s0[rf * 4 + r];
      float w = s1[rf * 4 + r];
      if (PASS == 1) {
#pragma unroll
        for (int m = 1; m < 16; m <<= 1) {
          v = fminf(v, __shfl_xor(v, m));
          w = fmaxf(w, __shfl_xor(w, m));
        }
        if (l15 == 0) {
          atomicMin(minord + grow, ford(v));
          atomicMax(maxord + grow, ford(w));
        }
      } else {
#pragma unroll
        for (int m = 1; m < 16; m <<= 1) {
          v += __shfl_xor(v, m);
          w += __shfl_xor(w, m);
        }
        if (l15 == 0) {
          atomicAdd(psum + grow, v);
          atomicAdd(nsum + grow, w);
        }
      }
    }
  }

  // ---- col reduction: over quads (rows), atomic per col (off-diag only) ----
  if (!diag) {
#pragma unroll
    for (int cf = 0; cf < 4; ++cf) {
      const int gcol = col0 + wc + cf * 16 + l15;
      float v = c0[cf];
      float w = c1[cf];
      if (PASS == 1) {
        v = fminf(v, __shfl_xor(v, 16)); v = fminf(v, __shfl_xor(v, 32));
        w = fmaxf(w, __shfl_xor(w, 16)); w = fmaxf(w, __shfl_xor(w, 32));
        if (quad == 0) {
          atomicMin(minord + gcol, ford(v));
          atomicMax(maxord + gcol, ford(w));
        }
      } else {
        v += __shfl_xor(v, 16); v += __shfl_xor(v, 32);
        w += __shfl_xor(w, 16); w += __shfl_xor(w, 32);
        if (quad == 0) {
          atomicAdd(psum + gcol, v);
          atomicAdd(nsum + gcol, w);
        }
      }
    }
  }
}

__global__ void finalize_kernel(const float* __restrict__ psum, const float* __restrict__ nsum,
                                float* __restrict__ out, int Bn) {
  __shared__ float sl[4], sc[4];
  float loss = 0.f, cnt = 0.f;
  for (int i = threadIdx.x; i < Bn; i += 256) {
    float p = psum[i], n = nsum[i];
    if (p > 0.f && n > 0.f) {
      loss += 0.5f * log1pf(p) + 0.02f * log1pf(n);
      cnt += 1.f;
    }
  }
#pragma unroll
  for (int m = 1; m < 64; m <<= 1) {
    loss += __shfl_xor(loss, m);
    cnt  += __shfl_xor(cnt, m);
  }
  int wave = threadIdx.x >> 6, lane = threadIdx.x & 63;
  if (lane == 0) { sl[wave] = loss; sc[wave] = cnt; }
  __syncthreads();
  if (threadIdx.x == 0) {
    float L = sl[0] + sl[1] + sl[2] + sl[3];
    float C = sc[0] + sc[1] + sc[2] + sc[3];
    out[0] = L / (float)Bn;
    out[1] = 1.0f - C / (float)Bn;
  }
}

extern "C" void kernel_launch(void* const* d_in, const int* in_sizes, int n_in,
                              void* d_out, int out_size, void* d_ws, size_t ws_size,
                              hipStream_t stream) {
  const float* feats  = (const float*)d_in[0];
  const int*   labels = (const int*)d_in[1];
  const int Bn = in_sizes[1];          // 8192
  float* out = (float*)d_out;

  unsigned* minord = (unsigned*)d_ws;
  unsigned* maxord = minord + Bn;
  float*    psum   = (float*)(maxord + Bn);
  float*    nsum   = psum + Bn;
  unsigned short* fb = (unsigned short*)(nsum + Bn);   // bf16 feats, 4MB

  init_kernel<<<(Bn + 255) / 256, 256, 0, stream>>>(minord, maxord, psum, nsum, Bn);

  int n4 = Bn * D / 4;
  convert_kernel<<<(n4 + 255) / 256, 256, 0, stream>>>(feats, fb, n4);

  pair_kernel<1><<<NBLK, 256, 0, stream>>>(fb, labels, minord, maxord, psum, nsum);
  pair_kernel<2><<<NBLK, 256, 0, stream>>>(fb, labels, minord, maxord, psum, nsum);
  finalize_kernel<<<1, 256, 0, stream>>>(psum, nsum, out, Bn);
}

// Round 4
// 207.937 us; speedup vs baseline: 1.2288x; 1.2288x over previous
//
#include <hip/hip_runtime.h>
#include <stdint.h>

// ---------------------------------------------------------------------------
// Speaker pairwise loss. sim = F·F^T symmetric: only 128x128 tiles J>=I (2080).
// NO atomics in hot kernels: each tile stores 256 partial stats (128 row-role +
// 128 col-role) with plain stores; reduce kernels fold 64 partials per row.
//   convert: fp32 -> bf16 once
//   pass1 -> pm0/pm1 (min-pos / max-neg partials); reduce1 -> tmn/tmx
//   pass2 -> pm0/pm1 (pos-sum / neg-sum partials); reduce2 -> psum/nsum
//   finalize -> loss, prec1
// Staging: global_load_lds width=16, BK=128 (2 chunks), XOR-swizzled unpadded.
// ws: fb bf16[B*D] | pm0[2080*256] | pm1[2080*256] | tmn[B] tmx[B] psum[B] nsum[B]
// ---------------------------------------------------------------------------

typedef __attribute__((ext_vector_type(8))) short short8;   // 8 bf16
typedef __attribute__((ext_vector_type(4))) float floatx4;  // MFMA C/D

constexpr int D = 256;
constexpr int BM = 128;
constexpr int NT = 64;                    // 8192/128
constexpr int NBLK = NT * (NT + 1) / 2;   // 2080

__device__ __forceinline__ int triBase(int I) { return I * (129 - I) / 2; }

__device__ __forceinline__ unsigned f2bf(float f) {  // fp32 -> bf16, RNE
  unsigned u = __float_as_uint(f);
  return (u + 0x7FFFu + ((u >> 16) & 1u)) >> 16;
}

__device__ __forceinline__ void gl_lds16(const void* g, void* l) {
  __builtin_amdgcn_global_load_lds(
      (const __attribute__((address_space(1))) unsigned int*)g,
      (__attribute__((address_space(3))) unsigned int*)l, 16, 0, 0);
}

__global__ void convert_kernel(const float* __restrict__ feats,
                               unsigned short* __restrict__ fb, int n4) {
  int i = blockIdx.x * blockDim.x + threadIdx.x;
  if (i < n4) {
    float4 v = ((const float4*)feats)[i];
    unsigned lo = f2bf(v.x) | (f2bf(v.y) << 16);
    unsigned hi = f2bf(v.z) | (f2bf(v.w) << 16);
    ((uint2*)fb)[i] = make_uint2(lo, hi);
  }
}

template <int PASS>
__global__ __launch_bounds__(256)
void pair_kernel(const unsigned short* __restrict__ fb, const int* __restrict__ labels,
                 const float* __restrict__ tmn, const float* __restrict__ tmx,
                 float* __restrict__ pm0, float* __restrict__ pm1) {
  __shared__ __align__(16) short AsBs[2 * BM * 128];   // 64KB: As | Bs (256B rows)
  short* As = AsBs;
  short* Bs = AsBs + BM * 128;
  float* sc = (float*)AsBs;                // epilogue scratch alias (512 floats)
  __shared__ int   labA[BM], labB[BM];
  __shared__ float tA0[BM], tA1[BM], tB0[BM], tB1[BM];

  // ---- triangular decode ----
  const int t = blockIdx.x;
  int I = (int)((129.0f - sqrtf(16641.0f - 8.0f * (float)t)) * 0.5f);
  while (I * (129 - I) / 2 > t) --I;
  while ((I + 1) * (129 - (I + 1)) / 2 <= t) ++I;
  const int J = I + (t - triBase(I));
  const bool diag = (I == J);
  const int row0 = I * BM, col0 = J * BM;

  const int tid  = threadIdx.x;
  const int lane = tid & 63;
  const int wave = tid >> 6;
  const int l15  = lane & 15;
  const int quad = lane >> 4;
  const int wr   = (wave >> 1) * 64;
  const int wc   = (wave & 1) * 64;

  const float ONE_EPS = 1.0f - 1e-5f;
  const float INF = __builtin_inff();

  if (tid < BM) {
    labA[tid] = labels[row0 + tid];
    labB[tid] = labels[col0 + tid];
    if (PASS == 2) {
      tA0[tid] = tmn[row0 + tid];
      tA1[tid] = tmx[row0 + tid];
      tB0[tid] = tmn[col0 + tid];
      tB1[tid] = tmx[col0 + tid];
    }
  }

  int arow[4], brow[4];
#pragma unroll
  for (int i = 0; i < 4; ++i) {
    arow[i] = wr + i * 16 + l15;
    brow[i] = wc + i * 16 + l15;
  }

  floatx4 acc[4][4];
#pragma unroll
  for (int rf = 0; rf < 4; ++rf)
#pragma unroll
    for (int cf = 0; cf < 4; ++cf)
      acc[rf][cf] = (floatx4)(0.f);

  // ---- K loop: 2 chunks of 128 ----
  for (int kc = 0; kc < 2; ++kc) {
#pragma unroll
    for (int i = 0; i < 8; ++i) {
      int r = i * 16 + wave * 4 + (lane >> 4);
      int s = lane & 15;
      int g = (s & 8) | ((s ^ r) & 7);                 // XOR swizzle (self-inverse)
      const char* ga = (const char*)fb + (((size_t)(row0 + r)) << 9) + (kc << 8) + (g << 4);
      const char* gb = (const char*)fb + (((size_t)(col0 + r)) << 9) + (kc << 8) + (g << 4);
      int ldo = ((i * 16 + wave * 4) << 8) + (lane << 4);   // == per-lane r*256+s*16
      gl_lds16(ga, (char*)As + ldo);
      gl_lds16(gb, (char*)Bs + ldo);
    }
    __syncthreads();
#pragma unroll
    for (int ks = 0; ks < 4; ++ks) {
      const int g = ks * 4 + quad;
      short8 a[4], b[4];
#pragma unroll
      for (int rf = 0; rf < 4; ++rf)
        a[rf] = *(const short8*)(As + arow[rf] * 128 + (((g & 8) | ((g ^ arow[rf]) & 7)) << 3));
#pragma unroll
      for (int cf = 0; cf < 4; ++cf)
        b[cf] = *(const short8*)(Bs + brow[cf] * 128 + (((g & 8) | ((g ^ brow[cf]) & 7)) << 3));
#pragma unroll
      for (int rf = 0; rf < 4; ++rf)
#pragma unroll
        for (int cf = 0; cf < 4; ++cf)
          acc[rf][cf] = __builtin_amdgcn_mfma_f32_16x16x32_bf16(a[rf], b[cf], acc[rf][cf], 0, 0, 0);
    }
    __syncthreads();
  }

  // ---- per-lane stats ----
  int labc[4];
  float tBn[4], tBx[4];
#pragma unroll
  for (int cf = 0; cf < 4; ++cf) {
    labc[cf] = labB[wc + cf * 16 + l15];
    if (PASS == 2) { tBn[cf] = tB0[wc + cf * 16 + l15]; tBx[cf] = tB1[wc + cf * 16 + l15]; }
  }

  float s0[16], s1[16], c0[4], c1[4];
#pragma unroll
  for (int i = 0; i < 16; ++i) {
    s0[i] = (PASS == 1) ? INF : 0.f;
    s1[i] = (PASS == 1) ? -INF : 0.f;
  }
#pragma unroll
  for (int i = 0; i < 4; ++i) {
    c0[i] = (PASS == 1) ? INF : 0.f;
    c1[i] = (PASS == 1) ? -INF : 0.f;
  }

#pragma unroll
  for (int rf = 0; rf < 4; ++rf) {
#pragma unroll
    for (int r = 0; r < 4; ++r) {
      const int ri = wr + rf * 16 + quad * 4 + r;
      const int lr = labA[ri];
      float tRn = 0.f, tRx = 0.f;
      if (PASS == 2) { tRn = tA0[ri]; tRx = tA1[ri]; }
#pragma unroll
      for (int cf = 0; cf < 4; ++cf) {
        float sim = acc[rf][cf][r];
        bool same = (lr == labc[cf]);
        bool posok = same && (sim < ONE_EPS);
        if (PASS == 1) {
          float pc = posok ? sim : INF;
          float nc = same ? -INF : sim;
          s0[rf * 4 + r] = fminf(s0[rf * 4 + r], pc);
          s1[rf * 4 + r] = fmaxf(s1[rf * 4 + r], nc);
          c0[cf] = fminf(c0[cf], pc);
          c1[cf] = fmaxf(c1[cf], nc);
        } else {
          if (posok) {
            float e = __expf(fmaf(-2.f, sim, 1.f));
            if (sim < tRx)      s0[rf * 4 + r] += e;
            if (sim < tBx[cf])  c0[cf] += e;
          } else if (!same) {
            float e = (sim > 0.22f) ? __expf(fmaf(50.f, sim, -25.f)) : 0.f;
            if (sim > tRn)      s1[rf * 4 + r] += 1e-30f + e;
            if (sim > tBn[cf])  c1[cf] += 1e-30f + e;
          }
        }
      }
    }
  }

  // ---- shuffle reductions: rows over l15, cols over quads ----
#pragma unroll
  for (int i = 0; i < 16; ++i) {
#pragma unroll
    for (int m = 1; m < 16; m <<= 1) {
      float v = __shfl_xor(s0[i], m), w = __shfl_xor(s1[i], m);
      s0[i] = (PASS == 1) ? fminf(s0[i], v) : (s0[i] + v);
      s1[i] = (PASS == 1) ? fmaxf(s1[i], w) : (s1[i] + w);
    }
  }
#pragma unroll
  for (int i = 0; i < 4; ++i) {
#pragma unroll
    for (int m = 16; m < 64; m <<= 1) {
      float v = __shfl_xor(c0[i], m), w = __shfl_xor(c1[i], m);
      c0[i] = (PASS == 1) ? fminf(c0[i], v) : (c0[i] + v);
      c1[i] = (PASS == 1) ? fmaxf(c1[i], w) : (c1[i] + w);
    }
  }

  // ---- cross-wave combine via LDS (As no longer needed), then plain stores ----
  float* rA = sc;          // [128] row stat 0
  float* rB = sc + 128;    // [128] row stat 1
  float* cA = sc + 256;    // [128] col stat 0
  float* cB = sc + 384;    // [128] col stat 1
  __syncthreads();         // ensure all ds_reads of As done before aliasing

  if (wc == 64 && l15 == 0) {     // waves 1,3: publish row halves
#pragma unroll
    for (int rf = 0; rf < 4; ++rf)
#pragma unroll
      for (int r = 0; r < 4; ++r) {
        int ri = wr + rf * 16 + quad * 4 + r;
        rA[ri] = s0[rf * 4 + r];
        rB[ri] = s1[rf * 4 + r];
      }
  }
  if (wr == 64 && quad == 0) {    // waves 2,3: publish col halves
#pragma unroll
    for (int cf = 0; cf < 4; ++cf) {
      int ci = wc + cf * 16 + l15;
      cA[ci] = c0[cf];
      cB[ci] = c1[cf];
    }
  }
  __syncthreads();

  if (wc == 0 && l15 == 0) {      // waves 0,2: combine + store 128 row partials
#pragma unroll
    for (int rf = 0; rf < 4; ++rf)
#pragma unroll
      for (int r = 0; r < 4; ++r) {
        int ri = wr + rf * 16 + quad * 4 + r;
        float v = s0[rf * 4 + r], w = s1[rf * 4 + r];
        v = (PASS == 1) ? fminf(v, rA[ri]) : (v + rA[ri]);
        w = (PASS == 1) ? fmaxf(w, rB[ri]) : (w + rB[ri]);
        pm0[(size_t)t * 256 + ri] = v;
        pm1[(size_t)t * 256 + ri] = w;
      }
  }
  if (wr == 0 && quad == 0) {     // waves 0,1: combine + store 128 col partials
#pragma unroll
    for (int cf = 0; cf < 4; ++cf) {
      int ci = wc + cf * 16 + l15;
      float v = c0[cf], w = c1[cf];
      v = (PASS == 1) ? fminf(v, cA[ci]) : (v + cA[ci]);
      w = (PASS == 1) ? fmaxf(w, cB[ci]) : (w + cB[ci]);
      if (diag) { v = (PASS == 1) ? INF : 0.f; w = (PASS == 1) ? -INF : 0.f; }
      pm0[(size_t)t * 256 + 128 + ci] = v;
      pm1[(size_t)t * 256 + 128 + ci] = w;
    }
  }
}

// fold 64 partials per row -> thresholds (pass1 output)
__global__ void reduce1_kernel(const float* __restrict__ pm0, const float* __restrict__ pm1,
                               float* __restrict__ tmn, float* __restrict__ tmx) {
  __shared__ float smn[128], smx[128];
  const int T = blockIdx.x;            // 64 blocks
  const int q = threadIdx.x & 127;
  const int h = threadIdx.x >> 7;
  const int nr = 64 - T;
  float mn = __builtin_inff(), mx = -__builtin_inff();
#pragma unroll 4
  for (int j = 0; j < 32; ++j) {
    int p = h * 32 + j;
    int t, slot;
    if (p < nr) { t = triBase(T) + p; slot = q; }
    else        { int Iq = p - nr; t = triBase(Iq) + (T - Iq); slot = 128 + q; }
    mn = fminf(mn, pm0[(size_t)t * 256 + slot]);
    mx = fmaxf(mx, pm1[(size_t)t * 256 + slot]);
  }
  if (h == 1) { smn[q] = mn; smx[q] = mx; }
  __syncthreads();
  if (h == 0) {
    mn = fminf(mn, smn[q]);
    mx = fmaxf(mx, smx[q]);
    tmn[T * 128 + q] = mn - 0.1f;   // min_pos - MARGIN (inf-safe)
    tmx[T * 128 + q] = mx + 0.1f;   // max_neg + MARGIN
  }
}

// fold 64 partials per row -> pos/neg sums (pass2 output)
__global__ void reduce2_kernel(const float* __restrict__ pm0, const float* __restrict__ pm1,
                               float* __restrict__ psum, float* __restrict__ nsum) {
  __shared__ float sp[128], sn[128];
  const int T = blockIdx.x;
  const int q = threadIdx.x & 127;
  const int h = threadIdx.x >> 7;
  const int nr = 64 - T;
  float p = 0.f, n = 0.f;
#pragma unroll 4
  for (int j = 0; j < 32; ++j) {
    int pp = h * 32 + j;
    int t, slot;
    if (pp < nr) { t = triBase(T) + pp; slot = q; }
    else         { int Iq = pp - nr; t = triBase(Iq) + (T - Iq); slot = 128 + q; }
    p += pm0[(size_t)t * 256 + slot];
    n += pm1[(size_t)t * 256 + slot];
  }
  if (h == 1) { sp[q] = p; sn[q] = n; }
  __syncthreads();
  if (h == 0) {
    psum[T * 128 + q] = p + sp[q];
    nsum[T * 128 + q] = n + sn[q];
  }
}

__global__ void finalize_kernel(const float* __restrict__ psum, const float* __restrict__ nsum,
                                float* __restrict__ out, int Bn) {
  __shared__ float sl[4], sc2[4];
  float loss = 0.f, cnt = 0.f;
  for (int i = threadIdx.x; i < Bn; i += 256) {
    float p = psum[i], n = nsum[i];
    if (p > 0.f && n > 0.f) {
      loss += 0.5f * log1pf(p) + 0.02f * log1pf(n);
      cnt += 1.f;
    }
  }
#pragma unroll
  for (int m = 1; m < 64; m <<= 1) {
    loss += __shfl_xor(loss, m);
    cnt  += __shfl_xor(cnt, m);
  }
  int wave = threadIdx.x >> 6, lane = threadIdx.x & 63;
  if (lane == 0) { sl[wave] = loss; sc2[wave] = cnt; }
  __syncthreads();
  if (threadIdx.x == 0) {
    float L = sl[0] + sl[1] + sl[2] + sl[3];
    float C = sc2[0] + sc2[1] + sc2[2] + sc2[3];
    out[0] = L / (float)Bn;
    out[1] = 1.0f - C / (float)Bn;
  }
}

extern "C" void kernel_launch(void* const* d_in, const int* in_sizes, int n_in,
                              void* d_out, int out_size, void* d_ws, size_t ws_size,
                              hipStream_t stream) {
  const float* feats  = (const float*)d_in[0];
  const int*   labels = (const int*)d_in[1];
  const int Bn = in_sizes[1];          // 8192
  float* out = (float*)d_out;

  unsigned short* fb = (unsigned short*)d_ws;                       // 4 MB
  float* pm0  = (float*)((char*)d_ws + (size_t)Bn * D * 2);         // 2080*256*4
  float* pm1  = pm0 + (size_t)NBLK * 256;
  float* tmn  = pm1 + (size_t)NBLK * 256;
  float* tmx  = tmn + Bn;
  float* psum = tmx + Bn;
  float* nsum = psum + Bn;

  int n4 = Bn * D / 4;
  convert_kernel<<<(n4 + 255) / 256, 256, 0, stream>>>(feats, fb, n4);

  pair_kernel<1><<<NBLK, 256, 0, stream>>>(fb, labels, nullptr, nullptr, pm0, pm1);
  reduce1_kernel<<<NT, 256, 0, stream>>>(pm0, pm1, tmn, tmx);
  pair_kernel<2><<<NBLK, 256, 0, stream>>>(fb, labels, tmn, tmx, pm0, pm1);
  reduce2_kernel<<<NT, 256, 0, stream>>>(pm0, pm1, psum, nsum);
  finalize_kernel<<<1, 256, 0, stream>>>(psum, nsum, out, Bn);
}